// Round 5
// baseline (1174.966 us; speedup 1.0000x reference)
//
#include <hip/hip_runtime.h>
#include <stdint.h>

#define T_TOK 4096
#define HDIM 2048
#define MDIM 1408
#define NEXP 28
#define TOPK 6
#define NPAIR (T_TOK*TOPK)   // 24576

typedef unsigned short u16;
typedef short short8 __attribute__((ext_vector_type(8)));
typedef float f32x4 __attribute__((ext_vector_type(4)));

__device__ __forceinline__ u16 f2bf(float x){
  unsigned int u = __float_as_uint(x);
  u += 0x7fffu + ((u >> 16) & 1u);
  return (u16)(u >> 16);
}
__device__ __forceinline__ float bf2f(unsigned int h){
  return __uint_as_float(h << 16);
}

__device__ __forceinline__ void gload16(const u16* g, u16* l){
  __builtin_amdgcn_global_load_lds((const __attribute__((address_space(1))) unsigned int*)g,
                                   (__attribute__((address_space(3))) unsigned int*)l,
                                   16, 0, 0);
}

// ---------------- x fp32 -> bf16 ----------------
__global__ __launch_bounds__(256) void cvt_kernel(const float* __restrict__ x,
                                                  u16* __restrict__ xb, int n8){
  int i = blockIdx.x*256 + threadIdx.x;
  if (i >= n8) return;
  const float4* s = (const float4*)x + (size_t)i*2;
  float4 a = s[0], b = s[1];
  unsigned int w0 = (unsigned)f2bf(a.x) | ((unsigned)f2bf(a.y)<<16);
  unsigned int w1 = (unsigned)f2bf(a.z) | ((unsigned)f2bf(a.w)<<16);
  unsigned int w2 = (unsigned)f2bf(b.x) | ((unsigned)f2bf(b.y)<<16);
  unsigned int w3 = (unsigned)f2bf(b.z) | ((unsigned)f2bf(b.w)<<16);
  uint4 o = {w0,w1,w2,w3};
  ((uint4*)xb)[i] = o;
}

// ---------------- transpose + convert: in [E][K][N] fp32 -> out [E][N][K] bf16 ----------------
__global__ __launch_bounds__(256) void transpose_cvt(const float* __restrict__ in,
                                                     u16* __restrict__ out, int K, int N){
  const int e = blockIdx.z;
  const int n0 = blockIdx.x*64, k0 = blockIdx.y*64;
  const float* src = in + ((size_t)e*K + k0)*N + n0;
  u16* dst = out + ((size_t)e*N + n0)*K + k0;
  __shared__ u16 td[64][65];
  const int tid = threadIdx.x;
  const int rk = tid>>4, rn = (tid&15)*4;
  #pragma unroll
  for (int i=0;i<4;i++){
    int k = rk + 16*i;
    float4 v = *(const float4*)(src + (size_t)k*N + rn);
    td[k][rn+0]=f2bf(v.x); td[k][rn+1]=f2bf(v.y);
    td[k][rn+2]=f2bf(v.z); td[k][rn+3]=f2bf(v.w);
  }
  __syncthreads();
  const int k8 = (tid&7)*8;
  #pragma unroll
  for (int i=0;i<2;i++){
    int n = (tid>>3) + 32*i;
    unsigned int w[4];
    #pragma unroll
    for (int j=0;j<4;j++)
      w[j] = (unsigned)td[k8+2*j][n] | ((unsigned)td[k8+2*j+1][n]<<16);
    uint4 o = {w[0],w[1],w[2],w[3]};
    *(uint4*)(dst + (size_t)n*K + k8) = o;
  }
}

// ---------------- gating ----------------
__global__ __launch_bounds__(256) void gate_kernel(const float* __restrict__ x,
                                                   const float* __restrict__ gw,
                                                   int* __restrict__ topk_idx,
                                                   float* __restrict__ topk_w,
                                                   int* __restrict__ counts){
  const int wave = threadIdx.x >> 6, lane = threadIdx.x & 63;
  const int t = blockIdx.x*4 + wave;
  const float* xr = x + (size_t)t*HDIM;
  float xv[32];
  #pragma unroll
  for (int i=0;i<32;i++) xv[i] = xr[lane + 64*i];
  float sc[NEXP];
  #pragma unroll
  for (int e=0;e<NEXP;e++){
    const float* g = gw + (size_t)e*HDIM + lane;
    float a = 0.f;
    #pragma unroll
    for (int i=0;i<32;i++) a += xv[i]*g[64*i];
    #pragma unroll
    for (int d=32; d>0; d>>=1) a += __shfl_xor(a, d);
    sc[e] = a;
  }
  float mx = sc[0];
  #pragma unroll
  for (int e=1;e<NEXP;e++) mx = fmaxf(mx, sc[e]);
  unsigned int mask=0; int bi[TOPK]; float bs[TOPK]; float bsum=0.f;
  #pragma unroll
  for (int k=0;k<TOPK;k++){
    float bm=-3.4e38f; int bj=0;
    #pragma unroll
    for (int e=0;e<NEXP;e++){
      bool ok = (((mask>>e)&1u)==0u) && (sc[e]>bm);
      bm = ok ? sc[e] : bm; bj = ok ? e : bj;
    }
    mask |= (1u<<bj);
    float s = expf(bm - mx);
    bi[k]=bj; bs[k]=s; bsum+=s;
  }
  if (lane==0){
    float inv = 1.f/(bsum + 1e-20f);
    #pragma unroll
    for (int k=0;k<TOPK;k++){
      topk_idx[t*TOPK+k]=bi[k];
      topk_w[t*TOPK+k]=bs[k]*inv;
      atomicAdd(&counts[bi[k]],1);
    }
  }
}

__global__ void scan_kernel(const int* __restrict__ counts, int* __restrict__ offsets,
                            int* __restrict__ cursor){
  int t = threadIdx.x;
  if (t < NEXP) cursor[t] = 0;
  if (t == 0){
    int s = 0;
    for (int e=0;e<NEXP;e++){ offsets[e]=s; s+=counts[e]; }
    offsets[NEXP]=s;
  }
}

__global__ __launch_bounds__(256) void fill_kernel(const int* __restrict__ topk_idx,
                                                   const float* __restrict__ topk_w,
                                                   const int* __restrict__ offsets,
                                                   int* __restrict__ cursor,
                                                   int* __restrict__ pair_token,
                                                   int* __restrict__ pos){
  int t = blockIdx.x*256 + threadIdx.x;
  if (t >= T_TOK) return;
  #pragma unroll
  for (int k=0;k<TOPK;k++){
    int e = topk_idx[t*TOPK+k];
    int c = atomicAdd(&cursor[e],1);
    int p = offsets[e]+c;
    pair_token[p]=t;
    pos[t*TOPK+k]=p;
  }
}

// ---------------- grouped GEMM: BM=256, BN=128, BK=64, 512 thr (8 waves 2Mx4N) ----------------
// Double-buffered LDS, late-wait counted pipeline:
//   per K-tile: [ds_read frags <- cur][SB0][gloads t+1 -> nxt][SB0][MFMA][vmcnt(0)][s_barrier]
// Wave's own vmcnt(0)+barrier => cross-wave staging visibility. Reads complete before MFMAs
// (auto lgkm) => before barrier => safe vs t+2 overwrite. Round-4 chunk XOR swizzle reused.
template<int NB, bool GATHER, int EPI, int NBN>
__global__ __launch_bounds__(512,2) void gemm5(
    const u16* __restrict__ Ab, const u16* __restrict__ B0, const u16* __restrict__ B1,
    u16* __restrict__ Hout,
    const int* __restrict__ counts, const int* __restrict__ offsets,
    const int* __restrict__ pair_token,
    int K, int N, int cpx)
{
  extern __shared__ u16 smem[];
  constexpr int BUFSZ = (NB==2) ? 32768 : 24576;   // u16 units

  const int bid = blockIdx.x;
  const int swz = (bid & 7)*cpx + (bid >> 3);
  const int rb  = swz & 7;               // 8 row-blocks fastest -> B-panel locality per XCD
  const int rest = swz >> 3;
  const int n0b = rest % NBN;
  const int e   = rest / NBN;

  const int cnt = counts[e];
  const int row0 = rb*256;
  if (row0 >= cnt) return;
  const int off = offsets[e];
  const int n0 = n0b*128;

  const int tid = threadIdx.x;
  const int lane = tid&63, wid = tid>>6;
  const int wm = wid>>2, wn = wid&3;     // 2M x 4N, per-wave 128x32
  const int lrow = lane&15, lgrp = lane>>4;

  // staging sources (swizzle baked into global chunk: u = (c&7)^(r&7))
  const u16* ap[4]; const u16* bp0[2]; const u16* bp1[2];
  #pragma unroll
  for (int i=0;i<4;i++){
    int c = tid + 512*i;                 // A: 2048 chunks, r=c>>3 in [0,256)
    int r = c>>3;
    int u = (c&7) ^ (r&7);
    int pr = off + min(row0 + r, cnt-1);
    const u16* arow = GATHER ? (Ab + (size_t)pair_token[pr]*K) : (Ab + (size_t)pr*K);
    ap[i] = arow + u*8;
  }
  #pragma unroll
  for (int i=0;i<2;i++){
    int c = tid + 512*i;                 // B: 1024 chunks, r=c>>3 in [0,128)
    int r = c>>3;
    int u = (c&7) ^ (r&7);
    size_t brow = (size_t)e*N + (size_t)(n0 + r);
    bp0[i] = B0 + brow*K + u*8;
    if (NB==2) bp1[i] = B1 + brow*K + u*8;
  }

  // fragment LDS addressing: row stride 64 u16; mr&7 == lrow&7 for all frags
  const int sA0 = ((lgrp)     ^ (lrow&7))*8;     // kh=0 swizzled chunk offset
  const int sA1 = ((4+lgrp)   ^ (lrow&7))*8;     // kh=1
  const int abase = (wm*128 + lrow)*64;
  const int bbase = 16384 + (wn*32 + lrow)*64;

  f32x4 acc0[8][2] = {};
  f32x4 acc1[8][2] = {};

  const int nt = K/64;

  // prologue: stage tile 0 into buf 0
  #pragma unroll
  for (int i=0;i<4;i++) gload16(ap[i], &smem[(tid+512*i)*8]);
  #pragma unroll
  for (int i=0;i<2;i++){
    gload16(bp0[i], &smem[16384 + (tid+512*i)*8]);
    if (NB==2) gload16(bp1[i], &smem[24576 + (tid+512*i)*8]);
  }
  asm volatile("s_waitcnt vmcnt(0)" ::: "memory");
  __builtin_amdgcn_s_barrier();

  for (int t=0; t<nt; ++t){
    const u16* sc = smem + (t&1)*BUFSZ;
    u16* sn = smem + ((t+1)&1)*BUFSZ;

    // 1) ds_read all fragments of current tile
    short8 af[2][8], b0f[2][2], b1f[2][2];
    #pragma unroll
    for (int fm=0;fm<8;fm++){
      af[0][fm] = *(const short8*)&sc[abase + fm*1024 + sA0];
      af[1][fm] = *(const short8*)&sc[abase + fm*1024 + sA1];
    }
    #pragma unroll
    for (int fn=0;fn<2;fn++){
      b0f[0][fn] = *(const short8*)&sc[bbase + fn*1024 + sA0];
      b0f[1][fn] = *(const short8*)&sc[bbase + fn*1024 + sA1];
      if (NB==2){
        b1f[0][fn] = *(const short8*)&sc[8192 + bbase + fn*1024 + sA0];
        b1f[1][fn] = *(const short8*)&sc[8192 + bbase + fn*1024 + sA1];
      }
    }
    __builtin_amdgcn_sched_barrier(0);

    // 2) issue next-tile staging (no wait here)
    if (t+1 < nt){
      const int kt = (t+1)*64;
      #pragma unroll
      for (int i=0;i<4;i++) gload16(ap[i] + kt, &sn[(tid+512*i)*8]);
      #pragma unroll
      for (int i=0;i<2;i++){
        gload16(bp0[i] + kt, &sn[16384 + (tid+512*i)*8]);
        if (NB==2) gload16(bp1[i] + kt, &sn[24576 + (tid+512*i)*8]);
      }
    }
    __builtin_amdgcn_sched_barrier(0);

    // 3) MFMAs (cover the in-flight loads)
    #pragma unroll
    for (int kh=0;kh<2;kh++){
      #pragma unroll
      for (int fm=0;fm<8;fm++){
        #pragma unroll
        for (int fn=0;fn<2;fn++){
          acc0[fm][fn] = __builtin_amdgcn_mfma_f32_16x16x32_bf16(af[kh][fm], b0f[kh][fn], acc0[fm][fn],0,0,0);
          if (NB==2)
            acc1[fm][fn] = __builtin_amdgcn_mfma_f32_16x16x32_bf16(af[kh][fm], b1f[kh][fn], acc1[fm][fn],0,0,0);
        }
      }
    }

    // 4) drain own loads, then tile-boundary barrier
    asm volatile("s_waitcnt vmcnt(0)" ::: "memory");
    __builtin_amdgcn_s_barrier();
  }

  // epilogue
  #pragma unroll
  for (int fm=0;fm<8;fm++){
    #pragma unroll
    for (int j=0;j<4;j++){
      int grow = wm*128 + fm*16 + lgrp*4 + j;
      if (row0+grow < cnt){
        int p = off + row0 + grow;
        u16* hrow = Hout + (size_t)p*N;
        #pragma unroll
        for (int fn=0;fn<2;fn++){
          int col = n0 + wn*32 + fn*16 + lrow;
          if (EPI==0){
            float g = acc0[fm][fn][j], u = acc1[fm][fn][j];
            hrow[col] = f2bf(g*u/(1.f+expf(-g)));
          } else {
            hrow[col] = f2bf(acc0[fm][fn][j]);
          }
        }
      }
    }
  }
}

// ---------------- combine ----------------
__global__ __launch_bounds__(256) void combine_kernel(const u16* __restrict__ pairbuf,
                                                      const int* __restrict__ pos,
                                                      const float* __restrict__ topk_w,
                                                      float* __restrict__ out){
  const int t = blockIdx.x;
  const int c = threadIdx.x*8;
  float acc[8] = {};
  #pragma unroll
  for (int k=0;k<TOPK;k++){
    int p = pos[t*TOPK+k];
    float w = topk_w[t*TOPK+k];
    uint4 v = *(const uint4*)&pairbuf[(size_t)p*HDIM + c];
    unsigned int ws_[4] = {v.x,v.y,v.z,v.w};
    #pragma unroll
    for (int j=0;j<4;j++){
      acc[2*j]   += w*bf2f(ws_[j]&0xffffu);
      acc[2*j+1] += w*bf2f(ws_[j]>>16);
    }
  }
  float4 o0 = {acc[0],acc[1],acc[2],acc[3]};
  float4 o1 = {acc[4],acc[5],acc[6],acc[7]};
  float* orow = out + (size_t)t*HDIM + c;
  *(float4*)orow = o0;
  *(float4*)(orow+4) = o1;
}

extern "C" void kernel_launch(void* const* d_in, const int* in_sizes, int n_in,
                              void* d_out, int out_size, void* d_ws, size_t ws_size,
                              hipStream_t stream) {
  const float* x  = (const float*)d_in[0];
  const float* gw = (const float*)d_in[1];
  const float* wg = (const float*)d_in[2];
  const float* wu = (const float*)d_in[3];
  const float* wd = (const float*)d_in[4];
  float* out = (float*)d_out;

  const size_t WT_BYTES = (size_t)NEXP*MDIM*HDIM*2;  // 161,480,704

  char* p = (char*)d_ws;
  u16* wg_t = (u16*)p;                 // [E][M][H] bf16
  u16* wd_t = (u16*)p;                 // [E][H][M] bf16 (overwrites wg_t after stage 1)
  p += WT_BYTES;
  u16* wu_t    = (u16*)p;              // [E][M][H] bf16
  u16* pairbuf = (u16*)p;              // [NPAIR][H] bf16 (overlays dead wu_t)
  p += WT_BYTES;
  u16* xb   = (u16*)p; p += (size_t)T_TOK*HDIM*2;   // 16.8 MB
  u16* hbuf = (u16*)p; p += (size_t)NPAIR*MDIM*2;   // 69.2 MB
  int*   topk_idx   = (int*)p;   p += NPAIR*4;
  float* topk_w     = (float*)p; p += NPAIR*4;
  int*   pair_token = (int*)p;   p += NPAIR*4;
  int*   pos        = (int*)p;   p += NPAIR*4;
  int*   counts     = (int*)p;   p += 128;
  int*   offsets    = (int*)p;   p += 128;
  int*   cursor     = (int*)p;   p += 128;

  hipMemsetAsync(counts, 0, 128, stream);
  cvt_kernel<<<T_TOK*HDIM/8/256, 256, 0, stream>>>(x, xb, T_TOK*HDIM/8);
  gate_kernel<<<T_TOK/4, 256, 0, stream>>>(x, gw, topk_idx, topk_w, counts);
  scan_kernel<<<1, 64, 0, stream>>>(counts, offsets, cursor);
  fill_kernel<<<T_TOK/256, 256, 0, stream>>>(topk_idx, topk_w, offsets, cursor, pair_token, pos);

  // weights -> bf16 transposed
  transpose_cvt<<<dim3(MDIM/64, HDIM/64, NEXP), 256, 0, stream>>>(wg, wg_t, HDIM, MDIM);
  transpose_cvt<<<dim3(MDIM/64, HDIM/64, NEXP), 256, 0, stream>>>(wu, wu_t, HDIM, MDIM);

  // stage 1: h = silu(x@wg) * (x@wu)  — ntile = 8*11*28 = 2464 (%8==0), 128KB LDS
  {
    int ntile = 8*(MDIM/128)*NEXP;
    gemm5<2,true,0,(MDIM/128)><<<ntile, 512, 131072, stream>>>(
        xb, wg_t, wu_t, hbuf, counts, offsets, pair_token, HDIM, MDIM, ntile/8);
  }

  // wd -> bf16 transposed
  transpose_cvt<<<dim3(HDIM/64, MDIM/64, NEXP), 256, 0, stream>>>(wd, wd_t, MDIM, HDIM);

  // stage 2: pairbuf = h @ wd — ntile = 8*16*28 = 3584 (%8==0), 96KB LDS
  {
    int ntile = 8*(HDIM/128)*NEXP;
    gemm5<1,false,1,(HDIM/128)><<<ntile, 512, 98304, stream>>>(
        hbuf, wd_t, nullptr, pairbuf, counts, offsets, pair_token, MDIM, HDIM, ntile/8);
  }

  combine_kernel<<<T_TOK, 256, 0, stream>>>(pairbuf, pos, topk_w, out);
}

// Round 6
// 1055.575 us; speedup vs baseline: 1.1131x; 1.1131x over previous
//
#include <hip/hip_runtime.h>
#include <stdint.h>

#define T_TOK 4096
#define HDIM 2048
#define MDIM 1408
#define NEXP 28
#define TOPK 6
#define NPAIR (T_TOK*TOPK)   // 24576

typedef unsigned short u16;
typedef short short8 __attribute__((ext_vector_type(8)));
typedef float f32x4 __attribute__((ext_vector_type(4)));

__device__ __forceinline__ u16 f2bf(float x){
  unsigned int u = __float_as_uint(x);
  u += 0x7fffu + ((u >> 16) & 1u);
  return (u16)(u >> 16);
}
__device__ __forceinline__ float bf2f(unsigned int h){
  return __uint_as_float(h << 16);
}

__device__ __forceinline__ void gload16(const u16* g, u16* l){
  __builtin_amdgcn_global_load_lds((const __attribute__((address_space(1))) unsigned int*)g,
                                   (__attribute__((address_space(3))) unsigned int*)l,
                                   16, 0, 0);
}

// ---------------- x fp32 -> bf16 ----------------
__global__ __launch_bounds__(256) void cvt_kernel(const float* __restrict__ x,
                                                  u16* __restrict__ xb, int n8){
  int i = blockIdx.x*256 + threadIdx.x;
  if (i >= n8) return;
  const float4* s = (const float4*)x + (size_t)i*2;
  float4 a = s[0], b = s[1];
  unsigned int w0 = (unsigned)f2bf(a.x) | ((unsigned)f2bf(a.y)<<16);
  unsigned int w1 = (unsigned)f2bf(a.z) | ((unsigned)f2bf(a.w)<<16);
  unsigned int w2 = (unsigned)f2bf(b.x) | ((unsigned)f2bf(b.y)<<16);
  unsigned int w3 = (unsigned)f2bf(b.z) | ((unsigned)f2bf(b.w)<<16);
  uint4 o = {w0,w1,w2,w3};
  ((uint4*)xb)[i] = o;
}

// ---------------- transpose + convert: in [E][K][N] fp32 -> out [E][N][K] bf16 ----------------
__global__ __launch_bounds__(256) void transpose_cvt(const float* __restrict__ in,
                                                     u16* __restrict__ out, int K, int N){
  const int e = blockIdx.z;
  const int n0 = blockIdx.x*64, k0 = blockIdx.y*64;
  const float* src = in + ((size_t)e*K + k0)*N + n0;
  u16* dst = out + ((size_t)e*N + n0)*K + k0;
  __shared__ u16 td[64][65];
  const int tid = threadIdx.x;
  const int rk = tid>>4, rn = (tid&15)*4;
  #pragma unroll
  for (int i=0;i<4;i++){
    int k = rk + 16*i;
    float4 v = *(const float4*)(src + (size_t)k*N + rn);
    td[k][rn+0]=f2bf(v.x); td[k][rn+1]=f2bf(v.y);
    td[k][rn+2]=f2bf(v.z); td[k][rn+3]=f2bf(v.w);
  }
  __syncthreads();
  const int k8 = (tid&7)*8;
  #pragma unroll
  for (int i=0;i<2;i++){
    int n = (tid>>3) + 32*i;
    unsigned int w[4];
    #pragma unroll
    for (int j=0;j<4;j++)
      w[j] = (unsigned)td[k8+2*j][n] | ((unsigned)td[k8+2*j+1][n]<<16);
    uint4 o = {w[0],w[1],w[2],w[3]};
    *(uint4*)(dst + (size_t)n*K + k8) = o;
  }
}

// ---------------- gating ----------------
__global__ __launch_bounds__(256) void gate_kernel(const float* __restrict__ x,
                                                   const float* __restrict__ gw,
                                                   int* __restrict__ topk_idx,
                                                   float* __restrict__ topk_w,
                                                   int* __restrict__ counts){
  const int wave = threadIdx.x >> 6, lane = threadIdx.x & 63;
  const int t = blockIdx.x*4 + wave;
  const float* xr = x + (size_t)t*HDIM;
  float xv[32];
  #pragma unroll
  for (int i=0;i<32;i++) xv[i] = xr[lane + 64*i];
  float sc[NEXP];
  #pragma unroll
  for (int e=0;e<NEXP;e++){
    const float* g = gw + (size_t)e*HDIM + lane;
    float a = 0.f;
    #pragma unroll
    for (int i=0;i<32;i++) a += xv[i]*g[64*i];
    #pragma unroll
    for (int d=32; d>0; d>>=1) a += __shfl_xor(a, d);
    sc[e] = a;
  }
  float mx = sc[0];
  #pragma unroll
  for (int e=1;e<NEXP;e++) mx = fmaxf(mx, sc[e]);
  unsigned int mask=0; int bi[TOPK]; float bs[TOPK]; float bsum=0.f;
  #pragma unroll
  for (int k=0;k<TOPK;k++){
    float bm=-3.4e38f; int bj=0;
    #pragma unroll
    for (int e=0;e<NEXP;e++){
      bool ok = (((mask>>e)&1u)==0u) && (sc[e]>bm);
      bm = ok ? sc[e] : bm; bj = ok ? e : bj;
    }
    mask |= (1u<<bj);
    float s = expf(bm - mx);
    bi[k]=bj; bs[k]=s; bsum+=s;
  }
  if (lane==0){
    float inv = 1.f/(bsum + 1e-20f);
    #pragma unroll
    for (int k=0;k<TOPK;k++){
      topk_idx[t*TOPK+k]=bi[k];
      topk_w[t*TOPK+k]=bs[k]*inv;
      atomicAdd(&counts[bi[k]],1);
    }
  }
}

__global__ void scan_kernel(const int* __restrict__ counts, int* __restrict__ offsets,
                            int* __restrict__ cursor){
  int t = threadIdx.x;
  if (t < NEXP) cursor[t] = 0;
  if (t == 0){
    int s = 0;
    for (int e=0;e<NEXP;e++){ offsets[e]=s; s+=counts[e]; }
    offsets[NEXP]=s;
  }
}

__global__ __launch_bounds__(256) void fill_kernel(const int* __restrict__ topk_idx,
                                                   const float* __restrict__ topk_w,
                                                   const int* __restrict__ offsets,
                                                   int* __restrict__ cursor,
                                                   int* __restrict__ pair_token,
                                                   int* __restrict__ pos){
  int t = blockIdx.x*256 + threadIdx.x;
  if (t >= T_TOK) return;
  #pragma unroll
  for (int k=0;k<TOPK;k++){
    int e = topk_idx[t*TOPK+k];
    int c = atomicAdd(&cursor[e],1);
    int p = offsets[e]+c;
    pair_token[p]=t;
    pos[t*TOPK+k]=p;
  }
}

// ---------------- grouped GEMM: BM=256, BN=128, BK=64, 512 thr (8 waves 2Mx4N) ----------------
// TRUE 2-tile-deep counted-vmcnt pipeline:
//   prologue: stage T0->buf0, T1->buf1; vmcnt(L); barrier
//   iter t:  [ds_read frags <- buf(t&1)] [lgkmcnt(0)] [barrier]
//            [issue T(t+2) -> buf(t&1)] [setprio1; 64 MFMA; setprio0]
//            [vmcnt(L): T(t+1) landed, T(t+2) stays in flight] [barrier]
// T(t+1)'s loads get a FULL iteration of cover (ds_read + MFMA phases) before the wait.
template<int NB, bool GATHER, int EPI, int NBN>
__global__ __launch_bounds__(512,2) void gemm6(
    const u16* __restrict__ Ab, const u16* __restrict__ B0, const u16* __restrict__ B1,
    u16* __restrict__ Hout,
    const int* __restrict__ counts, const int* __restrict__ offsets,
    const int* __restrict__ pair_token,
    int K, int N, int cpx)
{
  extern __shared__ u16 smem[];
  constexpr int BUFSZ = (NB==2) ? 32768 : 24576;   // u16 units

  const int bid = blockIdx.x;
  const int swz = (bid & 7)*cpx + (bid >> 3);
  const int rb  = swz & 7;               // 8 row-blocks fastest -> B-panel locality per XCD
  const int rest = swz >> 3;
  const int n0b = rest % NBN;
  const int e   = rest / NBN;

  const int cnt = counts[e];
  const int row0 = rb*256;
  if (row0 >= cnt) return;
  const int off = offsets[e];
  const int n0 = n0b*128;

  const int tid = threadIdx.x;
  const int lane = tid&63, wid = tid>>6;
  const int wm = wid>>2, wn = wid&3;     // 2M x 4N, per-wave 128x32
  const int lrow = lane&15, lgrp = lane>>4;

  // staging sources (swizzle baked into global chunk: u = (c&7)^(r&7))
  const u16* ap[4]; const u16* bp0[2]; const u16* bp1[2];
  #pragma unroll
  for (int i=0;i<4;i++){
    int c = tid + 512*i;                 // A: 2048 chunks, r=c>>3 in [0,256)
    int r = c>>3;
    int u = (c&7) ^ (r&7);
    int pr = off + min(row0 + r, cnt-1);
    const u16* arow = GATHER ? (Ab + (size_t)pair_token[pr]*K) : (Ab + (size_t)pr*K);
    ap[i] = arow + u*8;
  }
  #pragma unroll
  for (int i=0;i<2;i++){
    int c = tid + 512*i;                 // B: 1024 chunks, r=c>>3 in [0,128)
    int r = c>>3;
    int u = (c&7) ^ (r&7);
    size_t brow = (size_t)e*N + (size_t)(n0 + r);
    bp0[i] = B0 + brow*K + u*8;
    if (NB==2) bp1[i] = B1 + brow*K + u*8;
  }

  // fragment LDS addressing: row stride 64 u16; mr&7 == lrow&7 for all frags
  const int sA0 = ((lgrp)     ^ (lrow&7))*8;     // kh=0 swizzled chunk offset
  const int sA1 = ((4+lgrp)   ^ (lrow&7))*8;     // kh=1
  const int abase = (wm*128 + lrow)*64;
  const int bbase = 16384 + (wn*32 + lrow)*64;

  f32x4 acc0[8][2] = {};
  f32x4 acc1[8][2] = {};

  const int nt = K/64;

  // prologue: stage tiles 0 and 1
  #pragma unroll
  for (int i=0;i<4;i++) gload16(ap[i], &smem[(tid+512*i)*8]);
  #pragma unroll
  for (int i=0;i<2;i++){
    gload16(bp0[i], &smem[16384 + (tid+512*i)*8]);
    if (NB==2) gload16(bp1[i], &smem[24576 + (tid+512*i)*8]);
  }
  #pragma unroll
  for (int i=0;i<4;i++) gload16(ap[i] + 64, &smem[BUFSZ + (tid+512*i)*8]);
  #pragma unroll
  for (int i=0;i<2;i++){
    gload16(bp0[i] + 64, &smem[BUFSZ + 16384 + (tid+512*i)*8]);
    if (NB==2) gload16(bp1[i] + 64, &smem[BUFSZ + 24576 + (tid+512*i)*8]);
  }
  if (NB==2) asm volatile("s_waitcnt vmcnt(8)" ::: "memory");
  else       asm volatile("s_waitcnt vmcnt(6)" ::: "memory");
  __builtin_amdgcn_s_barrier();

  for (int t=0; t<nt; ++t){
    const u16* sc = smem + (t&1)*BUFSZ;
    u16* sn = (u16*)sc;                  // t+2 goes into the SAME buffer we just read

    // 1) ds_read all fragments of current tile
    short8 af[2][8], b0f[2][2], b1f[2][2];
    #pragma unroll
    for (int fm=0;fm<8;fm++){
      af[0][fm] = *(const short8*)&sc[abase + fm*1024 + sA0];
      af[1][fm] = *(const short8*)&sc[abase + fm*1024 + sA1];
    }
    #pragma unroll
    for (int fn=0;fn<2;fn++){
      b0f[0][fn] = *(const short8*)&sc[bbase + fn*1024 + sA0];
      b0f[1][fn] = *(const short8*)&sc[bbase + fn*1024 + sA1];
      if (NB==2){
        b1f[0][fn] = *(const short8*)&sc[8192 + bbase + fn*1024 + sA0];
        b1f[1][fn] = *(const short8*)&sc[8192 + bbase + fn*1024 + sA1];
      }
    }
    // all reads of this buffer done before anyone overwrites it
    asm volatile("s_waitcnt lgkmcnt(0)" ::: "memory");
    __builtin_amdgcn_sched_barrier(0);
    __builtin_amdgcn_s_barrier();

    // 2) issue T(t+2) into the just-freed buffer (no wait)
    if (t+2 < nt){
      const int kt = (t+2)*64;
      #pragma unroll
      for (int i=0;i<4;i++) gload16(ap[i] + kt, &sn[(tid+512*i)*8]);
      #pragma unroll
      for (int i=0;i<2;i++){
        gload16(bp0[i] + kt, &sn[16384 + (tid+512*i)*8]);
        if (NB==2) gload16(bp1[i] + kt, &sn[24576 + (tid+512*i)*8]);
      }
    }
    __builtin_amdgcn_sched_barrier(0);

    // 3) MFMA phase (covers T(t+1) completion and T(t+2) flight)
    __builtin_amdgcn_s_setprio(1);
    #pragma unroll
    for (int kh=0;kh<2;kh++){
      #pragma unroll
      for (int fm=0;fm<8;fm++){
        #pragma unroll
        for (int fn=0;fn<2;fn++){
          acc0[fm][fn] = __builtin_amdgcn_mfma_f32_16x16x32_bf16(af[kh][fm], b0f[kh][fn], acc0[fm][fn],0,0,0);
          if (NB==2)
            acc1[fm][fn] = __builtin_amdgcn_mfma_f32_16x16x32_bf16(af[kh][fm], b1f[kh][fn], acc1[fm][fn],0,0,0);
        }
      }
    }
    __builtin_amdgcn_s_setprio(0);

    // 4) wait for T(t+1) only (T(t+2) stays in flight), then publish
    if (t+1 < nt){
      if (t+2 < nt){
        if (NB==2) asm volatile("s_waitcnt vmcnt(8)" ::: "memory");
        else       asm volatile("s_waitcnt vmcnt(6)" ::: "memory");
      } else {
        asm volatile("s_waitcnt vmcnt(0)" ::: "memory");
      }
      __builtin_amdgcn_s_barrier();
    }
  }

  // epilogue
  #pragma unroll
  for (int fm=0;fm<8;fm++){
    #pragma unroll
    for (int j=0;j<4;j++){
      int grow = wm*128 + fm*16 + lgrp*4 + j;
      if (row0+grow < cnt){
        int p = off + row0 + grow;
        u16* hrow = Hout + (size_t)p*N;
        #pragma unroll
        for (int fn=0;fn<2;fn++){
          int col = n0 + wn*32 + fn*16 + lrow;
          if (EPI==0){
            float g = acc0[fm][fn][j], u = acc1[fm][fn][j];
            hrow[col] = f2bf(g*u/(1.f+expf(-g)));
          } else {
            hrow[col] = f2bf(acc0[fm][fn][j]);
          }
        }
      }
    }
  }
}

// ---------------- combine ----------------
__global__ __launch_bounds__(256) void combine_kernel(const u16* __restrict__ pairbuf,
                                                      const int* __restrict__ pos,
                                                      const float* __restrict__ topk_w,
                                                      float* __restrict__ out){
  const int t = blockIdx.x;
  const int c = threadIdx.x*8;
  float acc[8] = {};
  #pragma unroll
  for (int k=0;k<TOPK;k++){
    int p = pos[t*TOPK+k];
    float w = topk_w[t*TOPK+k];
    uint4 v = *(const uint4*)&pairbuf[(size_t)p*HDIM + c];
    unsigned int ws_[4] = {v.x,v.y,v.z,v.w};
    #pragma unroll
    for (int j=0;j<4;j++){
      acc[2*j]   += w*bf2f(ws_[j]&0xffffu);
      acc[2*j+1] += w*bf2f(ws_[j]>>16);
    }
  }
  float4 o0 = {acc[0],acc[1],acc[2],acc[3]};
  float4 o1 = {acc[4],acc[5],acc[6],acc[7]};
  float* orow = out + (size_t)t*HDIM + c;
  *(float4*)orow = o0;
  *(float4*)(orow+4) = o1;
}

extern "C" void kernel_launch(void* const* d_in, const int* in_sizes, int n_in,
                              void* d_out, int out_size, void* d_ws, size_t ws_size,
                              hipStream_t stream) {
  const float* x  = (const float*)d_in[0];
  const float* gw = (const float*)d_in[1];
  const float* wg = (const float*)d_in[2];
  const float* wu = (const float*)d_in[3];
  const float* wd = (const float*)d_in[4];
  float* out = (float*)d_out;

  const size_t WT_BYTES = (size_t)NEXP*MDIM*HDIM*2;  // 161,480,704

  char* p = (char*)d_ws;
  u16* wg_t = (u16*)p;                 // [E][M][H] bf16
  u16* wd_t = (u16*)p;                 // [E][H][M] bf16 (overwrites wg_t after stage 1)
  p += WT_BYTES;
  u16* wu_t    = (u16*)p;              // [E][M][H] bf16
  u16* pairbuf = (u16*)p;              // [NPAIR][H] bf16 (overlays dead wu_t)
  p += WT_BYTES;
  u16* xb   = (u16*)p; p += (size_t)T_TOK*HDIM*2;   // 16.8 MB
  u16* hbuf = (u16*)p; p += (size_t)NPAIR*MDIM*2;   // 69.2 MB
  int*   topk_idx   = (int*)p;   p += NPAIR*4;
  float* topk_w     = (float*)p; p += NPAIR*4;
  int*   pair_token = (int*)p;   p += NPAIR*4;
  int*   pos        = (int*)p;   p += NPAIR*4;
  int*   counts     = (int*)p;   p += 128;
  int*   offsets    = (int*)p;   p += 128;
  int*   cursor     = (int*)p;   p += 128;

  hipMemsetAsync(counts, 0, 128, stream);
  cvt_kernel<<<T_TOK*HDIM/8/256, 256, 0, stream>>>(x, xb, T_TOK*HDIM/8);
  gate_kernel<<<T_TOK/4, 256, 0, stream>>>(x, gw, topk_idx, topk_w, counts);
  scan_kernel<<<1, 64, 0, stream>>>(counts, offsets, cursor);
  fill_kernel<<<T_TOK/256, 256, 0, stream>>>(topk_idx, topk_w, offsets, cursor, pair_token, pos);

  // weights -> bf16 transposed
  transpose_cvt<<<dim3(MDIM/64, HDIM/64, NEXP), 256, 0, stream>>>(wg, wg_t, HDIM, MDIM);
  transpose_cvt<<<dim3(MDIM/64, HDIM/64, NEXP), 256, 0, stream>>>(wu, wu_t, HDIM, MDIM);

  // stage 1: h = silu(x@wg) * (x@wu)  — ntile = 8*11*28 = 2464 (%8==0), 128KB LDS
  {
    int ntile = 8*(MDIM/128)*NEXP;
    gemm6<2,true,0,(MDIM/128)><<<ntile, 512, 131072, stream>>>(
        xb, wg_t, wu_t, hbuf, counts, offsets, pair_token, HDIM, MDIM, ntile/8);
  }

  // wd -> bf16 transposed
  transpose_cvt<<<dim3(HDIM/64, MDIM/64, NEXP), 256, 0, stream>>>(wd, wd_t, MDIM, HDIM);

  // stage 2: pairbuf = h @ wd — ntile = 8*16*28 = 3584 (%8==0), 96KB LDS
  {
    int ntile = 8*(HDIM/128)*NEXP;
    gemm6<1,false,1,(HDIM/128)><<<ntile, 512, 98304, stream>>>(
        hbuf, wd_t, nullptr, pairbuf, counts, offsets, pair_token, MDIM, HDIM, ntile/8);
  }

  combine_kernel<<<T_TOK, 256, 0, stream>>>(pairbuf, pos, topk_w, out);
}